// Round 8
// baseline (126.779 us; speedup 1.0000x reference)
//
#include <hip/hip_runtime.h>
#include <math.h>

#define EDIM 256
#define LDIM 1024
#define HDIM 8
#define DDIM 32

typedef __attribute__((ext_vector_type(8))) short short8;
typedef __attribute__((ext_vector_type(4))) float f32x4;

__device__ inline unsigned short bf16h(float x) {
    unsigned u = __float_as_uint(x);
    return (unsigned short)((u + 0x7fff + ((u >> 16) & 1)) >> 16);   // RNE
}
__device__ inline float bf16tof(unsigned short h) {
    return __uint_as_float(((unsigned)h) << 16);
}
// split 8 fp32 (two float4) into hi/lo bf16 short8
__device__ inline void split8(const float4& a, const float4& b, short8& hi, short8& lo) {
    float v[8] = {a.x,a.y,a.z,a.w, b.x,b.y,b.z,b.w};
    #pragma unroll
    for (int j = 0; j < 8; ++j) {
        unsigned short hh = bf16h(v[j]);
        hi[j] = (short)hh;
        lo[j] = (short)bf16h(v[j] - bf16tof(hh));
    }
}

// ---------------------------------------------------------------------------
// proj_kernel (MFMA): dst(H,L,D) = X(L,E) @ W(E,E)^T per blockIdx.z.
// split-bf16 3-term MFMA; BOTH operands split in-register from fp32 (same
// bytes as pre-split bf16 pairs; kills the convertw launch). Direct global
// 16B frag loads, no LDS. 32x64 tile, 128 thr, grid (32,4,3)=384 blocks.
// z==0 fuses coeff[h][r] = sum_d q[r,h,d]*Wr[h*32+d].
// ---------------------------------------------------------------------------
__global__ __launch_bounds__(128) void proj_kernel(
    const float* __restrict__ Q, const float* __restrict__ K, const float* __restrict__ V,
    const float* __restrict__ Wq, const float* __restrict__ Wk, const float* __restrict__ Wv,
    const float* __restrict__ Wr,
    float* __restrict__ qT, float* __restrict__ kT, float* __restrict__ vT,
    float* __restrict__ coeff)
{
    const int z = blockIdx.z;
    const float* __restrict__ X   = (z == 0) ? Q : (z == 1) ? K : V;
    const float* __restrict__ Wfp = (z == 0) ? Wq : (z == 1) ? Wk : Wv;
    float* __restrict__ dst       = (z == 0) ? qT : (z == 1) ? kT : vT;

    const int n0 = blockIdx.x * 32;
    const int o0 = blockIdx.y * 64;
    const int wave = threadIdx.x >> 6;
    const int lane = threadIdx.x & 63;
    const int n16  = lane & 15;
    const int quad = lane >> 4;

    const int mrow = n0 + wave*16 + n16;

    f32x4 acc[4];
    #pragma unroll
    for (int t4 = 0; t4 < 4; ++t4) acc[t4] = (f32x4){0.f,0.f,0.f,0.f};

    #pragma unroll 2
    for (int kb = 0; kb < EDIM; kb += 32) {
        const float* xp = X + mrow*EDIM + kb + quad*8;
        float4 a0 = *(const float4*)xp;
        float4 a1 = *(const float4*)(xp + 4);
        short8 ah, al8;
        split8(a0, a1, ah, al8);
        #pragma unroll
        for (int t4 = 0; t4 < 4; ++t4) {
            const int orow = o0 + 16*t4 + n16;
            const float* wp = Wfp + orow*EDIM + kb + quad*8;
            float4 w0 = *(const float4*)wp;
            float4 w1 = *(const float4*)(wp + 4);
            short8 bh, bl;
            split8(w0, w1, bh, bl);
            acc[t4] = __builtin_amdgcn_mfma_f32_16x16x32_bf16(al8, bh, acc[t4], 0, 0, 0);
            acc[t4] = __builtin_amdgcn_mfma_f32_16x16x32_bf16(ah,  bl, acc[t4], 0, 0, 0);
            acc[t4] = __builtin_amdgcn_mfma_f32_16x16x32_bf16(ah,  bh, acc[t4], 0, 0, 0);
        }
    }

    // C/D layout: row = quad*4+i, col = n16 (per 16-col tile)
    #pragma unroll
    for (int t4 = 0; t4 < 4; ++t4) {
        const int o = o0 + 16*t4 + n16;
        const int h = o >> 5, d = o & 31;
        #pragma unroll
        for (int i = 0; i < 4; ++i) {
            const int r = n0 + wave*16 + quad*4 + i;
            dst[h*(LDIM*DDIM) + r*DDIM + d] = acc[t4][i];
        }
    }

    if (z == 0) {
        float wr[4];
        #pragma unroll
        for (int t4 = 0; t4 < 4; ++t4) wr[t4] = Wr[o0 + 16*t4 + n16];
        const int h0 = o0 >> 5;
        #pragma unroll
        for (int i = 0; i < 4; ++i) {
            float c0 = acc[0][i]*wr[0] + acc[1][i]*wr[1];
            float c1 = acc[2][i]*wr[2] + acc[3][i]*wr[3];
            #pragma unroll
            for (int off = 1; off < 16; off <<= 1) {
                c0 += __shfl_xor(c0, off, 64);
                c1 += __shfl_xor(c1, off, 64);
            }
            if (n16 == 0) {
                const int r = n0 + wave*16 + quad*4 + i;
                coeff[h0*LDIM + r]     = c0;
                coeff[(h0+1)*LDIM + r] = c1;
            }
        }
    }
}

// ---------------------------------------------------------------------------
// attn_kernel: flash attention, QK^T AND PV both on MFMA (split-bf16).
// Per 64-c k-tile: K staged as B-frags (as before); V staged as B-frags
// B[n=d][k=c] via c-major scalar loads; P transposed C/D->A-layout through a
// wave-private fp32 LDS region (no extra barrier); O accumulates in C/D
// regs, rescaled in-register by al[i] (same lane mapping -> no alph LDS).
// Grid (16, H, P). Writes unnormalized O partials + (m, l).
// NO device-scope fences (R6 lesson: __threadfence = cross-XCD L2 writeback,
// 15x slowdown).
// ---------------------------------------------------------------------------
__global__ __launch_bounds__(256, 4) void attn_kernel(
    const float* __restrict__ qT, const float* __restrict__ kT, const float* __restrict__ vT,
    const float* __restrict__ coeff, const float* __restrict__ pos,
    float* __restrict__ Op, float* __restrict__ Mp, float* __restrict__ Lp, int nkt)
{
    const int h   = blockIdx.y;
    const int q0  = blockIdx.x * 64;
    const int p   = blockIdx.z;
    const int kt0 = p * nkt * 64;
    const int tid  = threadIdx.x;
    const int wave = tid >> 6;
    const int lane = tid & 63;
    const int n    = lane & 15;
    const int quad = lane >> 4;
    const int qs0  = wave * 16;

    __shared__ __align__(16) short khi[4*64*8];   // QK B-frags, 4 col-tiles
    __shared__ __align__(16) short klo[4*64*8];
    __shared__ __align__(16) short vhi[4*64*8];   // PV B-frags, (cc,t) sets
    __shared__ __align__(16) short vlo[4*64*8];
    __shared__ float ps2[64*68];                  // P fp32 [q_local][c], pitch 68
    __shared__ float pk[64];

    // ---- Q fragments (A layout) ----
    short8 qhi, qlo;
    {
        const float* qp = qT + (h*LDIM + q0 + qs0 + n) * DDIM + quad*8;
        float4 qa = *(const float4*)qp;
        float4 qb = *(const float4*)(qp + 4);
        split8(qa, qb, qhi, qlo);
    }

    float pq[4], cq[4];
    #pragma unroll
    for (int i = 0; i < 4; ++i) {
        const int r = q0 + qs0 + 4*quad + i;
        pq[i] = pos[r];
        cq[i] = coeff[h*LDIM + r] * 0.0625f;
    }

    float m[4], l[4];
    #pragma unroll
    for (int i = 0; i < 4; ++i) { m[i] = -INFINITY; l[i] = 0.f; }

    // O accumulators: d-tile tt: col = 16*tt+n, rows = 4*quad+i
    f32x4 od[2];
    od[0] = (f32x4){0.f,0.f,0.f,0.f};
    od[1] = (f32x4){0.f,0.f,0.f,0.f};

    // K staging role
    const int cS = tid >> 2;
    const int dq = tid & 3;
    const int lane2 = (cS & 15) | (dq << 4);
    const int gS = cS >> 4;
    // V staging role: frag-set fs = cc*2 + t, slot lv
    const int fs  = tid >> 6;
    const int lv  = tid & 63;
    const int ccv = fs >> 1;
    const int tv  = fs & 1;
    const int cbase = ccv*32 + (lv >> 4)*8;   // c of element j = cbase + j
    const int dv    = tv*16 + (lv & 15);

    // ---- preload tile 0 ----
    float4 k0c, k1c; float vv[8]; float pkc = 0.f;
    {
        const float* kp = kT + (h*LDIM + kt0 + cS) * DDIM + dq*8;
        k0c = *(const float4*)kp; k1c = *(const float4*)(kp + 4);
        #pragma unroll
        for (int j = 0; j < 8; ++j)
            vv[j] = vT[(h*LDIM + kt0 + cbase + j)*DDIM + dv];
        if (tid < 64) pkc = pos[kt0 + tid];
    }

    for (int t = 0; t < nkt; ++t) {
        __syncthreads();   // (A) prev tile's LDS consumers done

        {   // stage K + V as split-bf16 B-frags
            short8 hi8, lo8;
            split8(k0c, k1c, hi8, lo8);
            *((short8*)&khi[(gS*64 + lane2)*8]) = hi8;
            *((short8*)&klo[(gS*64 + lane2)*8]) = lo8;
            float4 va; va.x = vv[0]; va.y = vv[1]; va.z = vv[2]; va.w = vv[3];
            float4 vb; vb.x = vv[4]; vb.y = vv[5]; vb.z = vv[6]; vb.w = vv[7];
            short8 vh8, vl8;
            split8(va, vb, vh8, vl8);
            *((short8*)&vhi[(fs*64 + lv)*8]) = vh8;
            *((short8*)&vlo[(fs*64 + lv)*8]) = vl8;
            if (tid < 64) pk[tid] = pkc;
        }

        // prefetch next tile (overlaps compute)
        float4 k0n, k1n; float vvn[8]; float pkn = 0.f;
        if (t + 1 < nkt) {
            const int kt = kt0 + (t+1) * 64;
            const float* kp = kT + (h*LDIM + kt + cS) * DDIM + dq*8;
            k0n = *(const float4*)kp; k1n = *(const float4*)(kp + 4);
            #pragma unroll
            for (int j = 0; j < 8; ++j)
                vvn[j] = vT[(h*LDIM + kt + cbase + j)*DDIM + dv];
            if (tid < 64) pkn = pos[kt + tid];
        }
        __syncthreads();   // (B) staging visible

        // ---- S = QK^T (3-term split-bf16), 4 col-tiles ----
        f32x4 Sf[4];
        #pragma unroll
        for (int t4 = 0; t4 < 4; ++t4) {
            short8 bhi = *((const short8*)&khi[(t4*64 + lane)*8]);
            short8 blo = *((const short8*)&klo[(t4*64 + lane)*8]);
            f32x4 acc = {0.f, 0.f, 0.f, 0.f};
            acc = __builtin_amdgcn_mfma_f32_16x16x32_bf16(qlo, bhi, acc, 0, 0, 0);
            acc = __builtin_amdgcn_mfma_f32_16x16x32_bf16(qhi, blo, acc, 0, 0, 0);
            acc = __builtin_amdgcn_mfma_f32_16x16x32_bf16(qhi, bhi, acc, 0, 0, 0);
            Sf[t4] = acc;
        }

        // ---- bias + online softmax (C/D: row=4quad+i, col=16t4+n) ----
        float ev[4][4];
        float rmax[4] = {-INFINITY, -INFINITY, -INFINITY, -INFINITY};
        #pragma unroll
        for (int t4 = 0; t4 < 4; ++t4) {
            const float pkt = pk[16*t4 + n];
            #pragma unroll
            for (int i = 0; i < 4; ++i) {
                float s = fmaf(Sf[t4][i], 0.0625f, cq[i] * __logf(fabsf(pq[i] - pkt) + 1.f));
                ev[t4][i] = s;
                rmax[i] = fmaxf(rmax[i], s);
            }
        }
        #pragma unroll
        for (int off = 1; off < 16; off <<= 1)
            #pragma unroll
            for (int i = 0; i < 4; ++i)
                rmax[i] = fmaxf(rmax[i], __shfl_xor(rmax[i], off, 64));

        float al[4], rsum[4];
        #pragma unroll
        for (int i = 0; i < 4; ++i) {
            const float mn = fmaxf(m[i], rmax[i]);
            al[i] = __expf(m[i] - mn);
            m[i] = mn;
            rsum[i] = 0.f;
        }
        #pragma unroll
        for (int t4 = 0; t4 < 4; ++t4)
            #pragma unroll
            for (int i = 0; i < 4; ++i) {
                float e = __expf(ev[t4][i] - m[i]);
                ev[t4][i] = e;
                rsum[i] += e;
            }
        #pragma unroll
        for (int off = 1; off < 16; off <<= 1)
            #pragma unroll
            for (int i = 0; i < 4; ++i)
                rsum[i] += __shfl_xor(rsum[i], off, 64);
        #pragma unroll
        for (int i = 0; i < 4; ++i) l[i] = l[i]*al[i] + rsum[i];

        // ---- write P to wave-private ps2[q][c] (pitch 68); 2-way banks ----
        #pragma unroll
        for (int t4 = 0; t4 < 4; ++t4)
            #pragma unroll
            for (int i = 0; i < 4; ++i)
                ps2[(qs0 + 4*quad + i)*68 + 16*t4 + n] = ev[t4][i];

        // ---- rescale O in-register (rows 4quad+i match al[i]) ----
        #pragma unroll
        for (int i = 0; i < 4; ++i) { od[0][i] *= al[i]; od[1][i] *= al[i]; }

        // ---- PV on MFMA: A-frag P (lane=q, k=c), B-frag V (lane=d, k=c) ----
        #pragma unroll
        for (int cc = 0; cc < 2; ++cc) {
            const float* pp = &ps2[(qs0 + n)*68 + cc*32 + quad*8];
            float4 p0 = *(const float4*)pp;
            float4 p1 = *(const float4*)(pp + 4);
            short8 phi, plo;
            split8(p0, p1, phi, plo);
            #pragma unroll
            for (int tt = 0; tt < 2; ++tt) {
                short8 bvh = *((const short8*)&vhi[((cc*2 + tt)*64 + lane)*8]);
                short8 bvl = *((const short8*)&vlo[((cc*2 + tt)*64 + lane)*8]);
                od[tt] = __builtin_amdgcn_mfma_f32_16x16x32_bf16(plo, bvh, od[tt], 0, 0, 0);
                od[tt] = __builtin_amdgcn_mfma_f32_16x16x32_bf16(phi, bvl, od[tt], 0, 0, 0);
                od[tt] = __builtin_amdgcn_mfma_f32_16x16x32_bf16(phi, bvh, od[tt], 0, 0, 0);
            }
        }

        k0c = k0n; k1c = k1n; pkc = pkn;
        #pragma unroll
        for (int j = 0; j < 8; ++j) vv[j] = vvn[j];
    }

    // ---- write partials (C/D layout: row=4quad+i, col=16tt+n) ----
    const int ph = p * HDIM + h;
    #pragma unroll
    for (int tt = 0; tt < 2; ++tt)
        #pragma unroll
        for (int i = 0; i < 4; ++i)
            Op[((size_t)ph*LDIM + q0 + qs0 + 4*quad + i)*DDIM + tt*16 + n] = od[tt][i];
    if (n == 0) {
        #pragma unroll
        for (int i = 0; i < 4; ++i) {
            const int r = q0 + qs0 + 4*quad + i;
            Mp[ph*LDIM + r] = m[i];
            Lp[ph*LDIM + r] = l[i];
        }
    }
}

// ---------------------------------------------------------------------------
// combine_kernel: A(L,E) = normalized combine of P attention partials (fp32).
// 65536 threads (256 blocks), one float4 of A per thread.
// ---------------------------------------------------------------------------
__global__ __launch_bounds__(256) void combine_kernel(
    const float* __restrict__ Op, const float* __restrict__ Mp, const float* __restrict__ Lp,
    int P, float* __restrict__ A)
{
    const int idx = blockIdx.x * 256 + threadIdx.x;   // 0..65535
    const int n  = idx >> 6;
    const int e4 = (idx & 63) * 4;
    const int h  = e4 >> 5;
    const int d  = e4 & 31;

    float mv[8], lv[8];
    float mx = -INFINITY;
    #pragma unroll
    for (int p = 0; p < 8; ++p) if (p < P) {
        mv[p] = Mp[(p*HDIM + h)*LDIM + n];
        lv[p] = Lp[(p*HDIM + h)*LDIM + n];
        mx = fmaxf(mx, mv[p]);
    }
    float s = 0.f;
    #pragma unroll
    for (int p = 0; p < 8; ++p) if (p < P) {
        float a = __expf(mv[p] - mx);
        mv[p] = a;
        s += a * lv[p];
    }
    const float inv = 1.f / s;

    float4 x; x.x = x.y = x.z = x.w = 0.f;
    #pragma unroll
    for (int p = 0; p < 8; ++p) if (p < P) {
        const float sp = mv[p] * inv;
        float4 xp = *(const float4*)(Op + ((size_t)(p*HDIM + h)*LDIM + n)*DDIM + d);
        x.x += sp*xp.x; x.y += sp*xp.y; x.z += sp*xp.z; x.w += sp*xp.w;
    }
    *(float4*)(A + n*EDIM + e4) = x;
}

// ---------------------------------------------------------------------------
// outproj_kernel (MFMA): out(L,E) = A(L,E) @ Wo(E,E)^T + bo; both operands
// split in-register from fp32. 32x32 tile, 128 thr, grid (32,8)=256 blocks.
// ---------------------------------------------------------------------------
__global__ __launch_bounds__(128) void outproj_kernel(
    const float* __restrict__ A, const float* __restrict__ Wo,
    const float* __restrict__ bo, float* __restrict__ out)
{
    const int n0 = blockIdx.x * 32;
    const int o0 = blockIdx.y * 32;
    const int wave = threadIdx.x >> 6;
    const int lane = threadIdx.x & 63;
    const int n16  = lane & 15;
    const int quad = lane >> 4;

    const int mrow = n0 + wave*16 + n16;

    f32x4 acc[2];
    acc[0] = (f32x4){0.f,0.f,0.f,0.f};
    acc[1] = (f32x4){0.f,0.f,0.f,0.f};

    #pragma unroll 2
    for (int kb = 0; kb < EDIM; kb += 32) {
        const float* ap = A + mrow*EDIM + kb + quad*8;
        float4 a0 = *(const float4*)ap;
        float4 a1 = *(const float4*)(ap + 4);
        short8 ah, al8;
        split8(a0, a1, ah, al8);
        #pragma unroll
        for (int t2 = 0; t2 < 2; ++t2) {
            const int orow = o0 + 16*t2 + n16;
            const float* wp = Wo + orow*EDIM + kb + quad*8;
            float4 w0 = *(const float4*)wp;
            float4 w1 = *(const float4*)(wp + 4);
            short8 bh, bl;
            split8(w0, w1, bh, bl);
            acc[t2] = __builtin_amdgcn_mfma_f32_16x16x32_bf16(al8, bh, acc[t2], 0, 0, 0);
            acc[t2] = __builtin_amdgcn_mfma_f32_16x16x32_bf16(ah,  bl, acc[t2], 0, 0, 0);
            acc[t2] = __builtin_amdgcn_mfma_f32_16x16x32_bf16(ah,  bh, acc[t2], 0, 0, 0);
        }
    }

    #pragma unroll
    for (int t2 = 0; t2 < 2; ++t2) {
        const int o = o0 + 16*t2 + n16;
        const float b = bo[o];
        #pragma unroll
        for (int i = 0; i < 4; ++i) {
            const int r = n0 + wave*16 + quad*4 + i;
            out[r*EDIM + o] = acc[t2][i] + b;
        }
    }
}

// ---------------------------------------------------------------------------
extern "C" void kernel_launch(void* const* d_in, const int* in_sizes, int n_in,
                              void* d_out, int out_size, void* d_ws, size_t ws_size,
                              hipStream_t stream) {
    const float* V   = (const float*)d_in[0];
    const float* K   = (const float*)d_in[1];
    const float* Q   = (const float*)d_in[2];
    const float* pos = (const float*)d_in[3];
    const float* Wq  = (const float*)d_in[4];
    const float* Wk  = (const float*)d_in[5];
    const float* Wv  = (const float*)d_in[6];
    const float* Wr  = (const float*)d_in[7];
    const float* Wo  = (const float*)d_in[8];
    const float* bo  = (const float*)d_in[9];
    float* out = (float*)d_out;
    float* ws  = (float*)d_ws;

    // ---- workspace layout (float units) ----
    float* qT    = ws;                 // reused as A after attn
    float* kT    = ws + 262144;
    float* vT    = ws + 524288;
    float* coeff = ws + 786432;
    float* Op    = ws + 794624;

    auto need = [](int P) -> size_t {
        return (size_t)(794624 + P*278528) * 4;
    };
    int P = 2;
    if (ws_size >= need(8)) P = 8;
    else if (ws_size >= need(4)) P = 4;

    float* Mp = Op + (size_t)P * 262144;
    float* Lp = Mp + (size_t)P * 8192;
    float* A  = qT;                    // qT dead after attn_kernel

    proj_kernel    <<<dim3(32, 4, 3), 128, 0, stream>>>(Q, K, V, Wq, Wk, Wv, Wr,
                                                        qT, kT, vT, coeff);
    attn_kernel    <<<dim3(16, 8, P), 256, 0, stream>>>(qT, kT, vT, coeff, pos,
                                                        Op, Mp, Lp, 16 / P);
    combine_kernel <<<dim3(256),      256, 0, stream>>>(Op, Mp, Lp, P, A);
    outproj_kernel <<<dim3(32, 8),    128, 0, stream>>>(A, Wo, bo, out);
}